// Round 3
// baseline (266.684 us; speedup 1.0000x reference)
//
#include <hip/hip_runtime.h>

// CustomGraphConv (all fp32): msg[e,o] = sum_{a,i} ea[e,a]*W[a,o,i]*x[src_e,i];
// aggr = scatter_add(msg, dst); out = relu(aggr + bias).
// x[N,16] f32, edge_index[2,E] int (32 or 64 — runtime-detected), edge_attr[E,8] f32,
// W[8,16,16] f32, bias[16] f32, out[N,16] f32.
//
// Accumulate fp32 directly in d_out (it is exactly [N,16] fp32), then in-place bias+relu.
// Path A (ws >= 51.2MB+pad): y[n,o,a] = sum_i W[a,o,i]*x[n,i]; per-(e,o) dot8 scatter.
// Path B: direct einsum per (e,o).

#define IN_C 16
#define OUT_C 16
#define NA 8

// ---------- int64-vs-int32 edge_index detection ----------
// int64 indices < 2^31: every odd 32-bit word (high half) is 0. Sample 256 odd words.
__global__ void k_detect(const int* __restrict__ ei, int half_words, int* __restrict__ flag) {
    __shared__ int any_nonzero;
    if (threadIdx.x == 0) any_nonzero = 0;
    __syncthreads();
    int step = half_words / 256;
    if (step < 1) step = 1;
    long long pos = 1 + 2LL * (long long)threadIdx.x * step;  // odd positions
    if (pos < 2LL * half_words && ei[pos] != 0) atomicOr(&any_nonzero, 1);
    __syncthreads();
    if (threadIdx.x == 0) flag[0] = (any_nonzero == 0) ? 1 : 0;  // 1 => int64
}

__device__ __forceinline__ void load_edge(const int* __restrict__ ei, const int* __restrict__ flag,
                                          long long E, long long e, int& src, int& dst) {
    int is64 = flag ? flag[0] : 0;
    if (is64) { src = ei[2 * e]; dst = ei[2 * (E + e)]; }
    else      { src = ei[e];     dst = ei[E + e]; }
}

// ---------- W -> LDS, layout Wl[o][a*16+i], pad 129 (bank-conflict-free: bank = (o + k) & 31) ----------
#define LOAD_W_LDS()                                               \
    __shared__ float Wl[OUT_C][129];                               \
    for (int k = threadIdx.x; k < NA * OUT_C * IN_C; k += 256) {   \
        int a = k >> 8, o = (k >> 4) & 15, i = k & 15;             \
        Wl[o][a * IN_C + i] = W[k];                                \
    }                                                              \
    __syncthreads();

// ---------- path A stage 1: y[n][o][a] = dot(W[a,o,:], x[n,:]) ----------
__global__ void __launch_bounds__(256) k_stage1(
    const float* __restrict__ x, const float* __restrict__ W,
    float* __restrict__ y, int n_nodes) {
    LOAD_W_LDS();
    int idx = blockIdx.x * 256 + threadIdx.x;
    if (idx >= n_nodes * OUT_C) return;
    int n = idx >> 4, o = idx & 15;
    const float4* xp = reinterpret_cast<const float4*>(x + (size_t)n * IN_C);
    float4 x0 = xp[0], x1 = xp[1], x2 = xp[2], x3 = xp[3];
    float xv[16] = {x0.x, x0.y, x0.z, x0.w, x1.x, x1.y, x1.z, x1.w,
                    x2.x, x2.y, x2.z, x2.w, x3.x, x3.y, x3.z, x3.w};
    float4* yp = reinterpret_cast<float4*>(y + ((size_t)n * OUT_C + o) * NA);
    float acc[NA];
#pragma unroll
    for (int a = 0; a < NA; ++a) {
        float s = 0.f;
#pragma unroll
        for (int i = 0; i < IN_C; ++i) s = fmaf(Wl[o][a * IN_C + i], xv[i], s);
        acc[a] = s;
    }
    yp[0] = make_float4(acc[0], acc[1], acc[2], acc[3]);
    yp[1] = make_float4(acc[4], acc[5], acc[6], acc[7]);
}

// ---------- path A stage 2: per-(e,o) dot8 + scatter into out ----------
__global__ void __launch_bounds__(256) k_stage2(
    const int* __restrict__ ei, const float* __restrict__ ea,
    const float* __restrict__ y, float* __restrict__ out,
    const int* __restrict__ flag, int n_edges) {
    long long idx = (long long)blockIdx.x * 256 + threadIdx.x;
    if (idx >= (long long)n_edges * OUT_C) return;
    long long e = idx >> 4;
    int o = (int)(idx & 15);
    int src, dst;
    load_edge(ei, flag, n_edges, e, src, dst);
    const float4* ap = reinterpret_cast<const float4*>(ea + e * NA);
    float4 a0 = ap[0], a1 = ap[1];
    const float4* yp = reinterpret_cast<const float4*>(y + ((size_t)src * OUT_C + o) * NA);
    float4 y0 = yp[0], y1 = yp[1];
    float s = a0.x * y0.x;
    s = fmaf(a0.y, y0.y, s); s = fmaf(a0.z, y0.z, s); s = fmaf(a0.w, y0.w, s);
    s = fmaf(a1.x, y1.x, s); s = fmaf(a1.y, y1.y, s);
    s = fmaf(a1.z, y1.z, s); s = fmaf(a1.w, y1.w, s);
    unsafeAtomicAdd(out + (size_t)dst * OUT_C + o, s);
}

// ---------- path B: direct einsum per (e,o) ----------
__global__ void __launch_bounds__(256) k_direct(
    const float* __restrict__ x, const int* __restrict__ ei,
    const float* __restrict__ ea, const float* __restrict__ W,
    float* __restrict__ out, const int* __restrict__ flag, int n_edges) {
    LOAD_W_LDS();
    long long idx = (long long)blockIdx.x * 256 + threadIdx.x;
    if (idx >= (long long)n_edges * OUT_C) return;
    long long e = idx >> 4;
    int o = (int)(idx & 15);
    int src, dst;
    load_edge(ei, flag, n_edges, e, src, dst);
    const float4* ap = reinterpret_cast<const float4*>(ea + e * NA);
    float4 a0 = ap[0], a1 = ap[1];
    float av[NA] = {a0.x, a0.y, a0.z, a0.w, a1.x, a1.y, a1.z, a1.w};
    const float4* xp = reinterpret_cast<const float4*>(x + (size_t)src * IN_C);
    float4 x0 = xp[0], x1 = xp[1], x2 = xp[2], x3 = xp[3];
    float xv[16] = {x0.x, x0.y, x0.z, x0.w, x1.x, x1.y, x1.z, x1.w,
                    x2.x, x2.y, x2.z, x2.w, x3.x, x3.y, x3.z, x3.w};
    float s = 0.f;
#pragma unroll
    for (int a = 0; a < NA; ++a) {
        float d = 0.f;
#pragma unroll
        for (int i = 0; i < IN_C; ++i) d = fmaf(Wl[o][a * IN_C + i], xv[i], d);
        s = fmaf(av[a], d, s);
    }
    unsafeAtomicAdd(out + (size_t)dst * OUT_C + o, s);
}

// ---------- finalize: in-place out = relu(out + bias), thread = 4 floats ----------
__global__ void __launch_bounds__(256) k_bias_relu(
    const float* __restrict__ bias, float* __restrict__ out, int total4) {
    int idx = blockIdx.x * 256 + threadIdx.x;
    if (idx >= total4) return;
    int j0 = (idx & 3) * 4;
    const float4 b = reinterpret_cast<const float4*>(bias + j0)[0];
    float4* op = reinterpret_cast<float4*>(out) + idx;
    float4 v = op[0];
    v.x = fmaxf(v.x + b.x, 0.f);
    v.y = fmaxf(v.y + b.y, 0.f);
    v.z = fmaxf(v.z + b.z, 0.f);
    v.w = fmaxf(v.w + b.w, 0.f);
    op[0] = v;
}

extern "C" void kernel_launch(void* const* d_in, const int* in_sizes, int n_in,
                              void* d_out, int out_size, void* d_ws, size_t ws_size,
                              hipStream_t stream) {
    const float* x    = (const float*)d_in[0];   // [N,16] f32
    const int*   ei   = (const int*)d_in[1];     // [2,E] int (32 or 64, detected)
    const float* ea   = (const float*)d_in[2];   // [E,8] f32
    const float* W    = (const float*)d_in[3];   // [8,16,16] f32
    const float* bias = (const float*)d_in[4];   // [16] f32
    float* out = (float*)d_out;

    int n_nodes = in_sizes[0] / IN_C;
    int n_edges = in_sizes[2] / NA;

    // flag in first 64B of ws (recomputed every call; ws is re-poisoned each call)
    int* flag = (ws_size >= 64) ? (int*)d_ws : nullptr;
    if (flag) k_detect<<<1, 256, 0, stream>>>(ei, n_edges, flag);

    // zero the fp32 accumulator (= d_out itself)
    hipMemsetAsync(d_out, 0, (size_t)n_nodes * OUT_C * sizeof(float), stream);

    long long tE = (long long)n_edges * OUT_C;
    int gE = (int)((tE + 255) / 256);

    size_t y_bytes = (size_t)n_nodes * OUT_C * NA * sizeof(float);  // 51.2 MB
    if (ws_size >= 64 + y_bytes) {
        float* y = (float*)((char*)d_ws + 64);
        int t1 = n_nodes * OUT_C;
        k_stage1<<<(t1 + 255) / 256, 256, 0, stream>>>(x, W, y, n_nodes);
        k_stage2<<<gE, 256, 0, stream>>>(ei, ea, y, out, flag, n_edges);
    } else {
        k_direct<<<gE, 256, 0, stream>>>(x, ei, ea, W, out, flag, n_edges);
    }

    int t4 = (n_nodes * OUT_C) / 4;
    k_bias_relu<<<(t4 + 255) / 256, 256, 0, stream>>>(bias, out, t4);
}

// Round 4
// 220.488 us; speedup vs baseline: 1.2095x; 1.2095x over previous
//
#include <hip/hip_runtime.h>

// CustomGraphConv (fp32 in/out, int64 edge_index runtime-confirmed):
//   msg[e,o] = sum_{a,i} ea[e,a]*W[a,o,i]*x[src_e,i]; scatter-add to dst; relu(+bias).
// Factorized: y[n,o,a] = sum_i W[a,o,i]*x[n,i]  (stored BF16: 256 B/node row,
// 25.6 MB footprint) -> stage2 per-(e,o): dot8(ea[e,:], y[src,o,:]) + atomicAdd.
// fp32 accumulation happens directly in d_out ([N,16] fp32), then in-place bias+relu.

#define IN_C 16
#define OUT_C 16
#define NA 8

typedef unsigned short u16;

__device__ __forceinline__ float bfbits(unsigned hi) {
    union { unsigned u; float f; } c; c.u = hi; return c.f;
}
__device__ __forceinline__ u16 f2bf(float f) {
    union { float f; unsigned u; } c; c.f = f;
    unsigned u = c.u + (0x7fffu + ((c.u >> 16) & 1u));   // RNE
    return (u16)(u >> 16);
}

// ---------- stage 1: y_bf16[n][o][a] = dot(W[a,o,:], x[n,:]); block 0 also detects int64 ----------
__global__ void __launch_bounds__(256) k_stage1(
    const float* __restrict__ x, const float* __restrict__ W,
    const int* __restrict__ ei, long long n_edges,
    u16* __restrict__ y, int* __restrict__ flag, int n_nodes) {
    // --- int64 detection (block 0 only): if int64, odd 32-bit words in the first
    // 2E words are high-halves of src indices -> all zero. int32: random ids.
    __shared__ int s_nz;
    if (blockIdx.x == 0) {
        if (threadIdx.x == 0) s_nz = 0;
        __syncthreads();
        long long lim = 2 * n_edges;                 // words valid under BOTH dtypes
        long long step = (n_edges / 256) | 1;
        long long pos = 1 + 2 * (long long)threadIdx.x * step;
        if (pos < lim && ei[pos] != 0) atomicOr(&s_nz, 1);
        __syncthreads();
        if (threadIdx.x == 0) flag[0] = (s_nz == 0) ? 1 : 0;   // 1 => int64
    }

    __shared__ float Wl[OUT_C][129];
    for (int k = threadIdx.x; k < NA * OUT_C * IN_C; k += 256) {
        int a = k >> 8, o = (k >> 4) & 15, i = k & 15;
        Wl[o][a * IN_C + i] = W[k];
    }
    __syncthreads();

    int idx = blockIdx.x * 256 + threadIdx.x;
    if (idx >= n_nodes * OUT_C) return;
    int n = idx >> 4, o = idx & 15;
    const float4* xp = reinterpret_cast<const float4*>(x + (size_t)n * IN_C);
    float4 x0 = xp[0], x1 = xp[1], x2 = xp[2], x3 = xp[3];
    float xv[16] = {x0.x, x0.y, x0.z, x0.w, x1.x, x1.y, x1.z, x1.w,
                    x2.x, x2.y, x2.z, x2.w, x3.x, x3.y, x3.z, x3.w};
    float acc[NA];
#pragma unroll
    for (int a = 0; a < NA; ++a) {
        float s = 0.f;
#pragma unroll
        for (int i = 0; i < IN_C; ++i) s = fmaf(Wl[o][a * IN_C + i], xv[i], s);
        acc[a] = s;
    }
    union { uint4 u; u16 h[8]; } pk;
#pragma unroll
    for (int a = 0; a < NA; ++a) pk.h[a] = f2bf(acc[a]);
    reinterpret_cast<uint4*>(y + ((size_t)n * OUT_C + o) * NA)[0] = pk.u;
}

// ---------- stage 2: per-(e,o) dot8(ea, y_bf16[src,o,:]) + scatter ----------
__global__ void __launch_bounds__(256) k_stage2(
    const int* __restrict__ ei, const float* __restrict__ ea,
    const u16* __restrict__ y, float* __restrict__ out,
    const int* __restrict__ flag, long long n_edges) {
    long long idx = (long long)blockIdx.x * 256 + threadIdx.x;
    if (idx >= n_edges * OUT_C) return;
    long long e = idx >> 4;
    int o = (int)(idx & 15);
    int src, dst;
    if (flag[0]) { src = ei[2 * e]; dst = ei[2 * (n_edges + e)]; }
    else         { src = ei[e];     dst = ei[n_edges + e]; }

    const float4* ap = reinterpret_cast<const float4*>(ea + e * NA);
    float4 a0 = ap[0], a1 = ap[1];
    uint4 yu = reinterpret_cast<const uint4*>(y + ((size_t)src * OUT_C + o) * NA)[0];

    float s =      bfbits(yu.x << 16)        * a0.x;
    s = fmaf(bfbits(yu.x & 0xffff0000u), a0.y, s);
    s = fmaf(bfbits(yu.y << 16),         a0.z, s);
    s = fmaf(bfbits(yu.y & 0xffff0000u), a0.w, s);
    s = fmaf(bfbits(yu.z << 16),         a1.x, s);
    s = fmaf(bfbits(yu.z & 0xffff0000u), a1.y, s);
    s = fmaf(bfbits(yu.w << 16),         a1.z, s);
    s = fmaf(bfbits(yu.w & 0xffff0000u), a1.w, s);

    unsafeAtomicAdd(out + (size_t)dst * OUT_C + o, s);
}

// ---------- fallback (tiny ws): direct einsum, assumes int64 (reference truth) ----------
__global__ void __launch_bounds__(256) k_direct(
    const float* __restrict__ x, const int* __restrict__ ei,
    const float* __restrict__ ea, const float* __restrict__ W,
    float* __restrict__ out, long long n_edges) {
    __shared__ float Wl[OUT_C][129];
    for (int k = threadIdx.x; k < NA * OUT_C * IN_C; k += 256) {
        int a = k >> 8, o = (k >> 4) & 15, i = k & 15;
        Wl[o][a * IN_C + i] = W[k];
    }
    __syncthreads();
    long long idx = (long long)blockIdx.x * 256 + threadIdx.x;
    if (idx >= n_edges * OUT_C) return;
    long long e = idx >> 4;
    int o = (int)(idx & 15);
    int src = ei[2 * e], dst = ei[2 * (n_edges + e)];
    const float4* ap = reinterpret_cast<const float4*>(ea + e * NA);
    float4 a0 = ap[0], a1 = ap[1];
    float av[NA] = {a0.x, a0.y, a0.z, a0.w, a1.x, a1.y, a1.z, a1.w};
    const float4* xp = reinterpret_cast<const float4*>(x + (size_t)src * IN_C);
    float4 x0 = xp[0], x1 = xp[1], x2 = xp[2], x3 = xp[3];
    float xv[16] = {x0.x, x0.y, x0.z, x0.w, x1.x, x1.y, x1.z, x1.w,
                    x2.x, x2.y, x2.z, x2.w, x3.x, x3.y, x3.z, x3.w};
    float s = 0.f;
#pragma unroll
    for (int a = 0; a < NA; ++a) {
        float d = 0.f;
#pragma unroll
        for (int i = 0; i < IN_C; ++i) d = fmaf(Wl[o][a * IN_C + i], xv[i], d);
        s = fmaf(av[a], d, s);
    }
    unsafeAtomicAdd(out + (size_t)dst * OUT_C + o, s);
}

// ---------- finalize: in-place out = relu(out + bias) ----------
__global__ void __launch_bounds__(256) k_bias_relu(
    const float* __restrict__ bias, float* __restrict__ out, int total4) {
    int idx = blockIdx.x * 256 + threadIdx.x;
    if (idx >= total4) return;
    int j0 = (idx & 3) * 4;
    const float4 b = reinterpret_cast<const float4*>(bias + j0)[0];
    float4* op = reinterpret_cast<float4*>(out) + idx;
    float4 v = op[0];
    v.x = fmaxf(v.x + b.x, 0.f);
    v.y = fmaxf(v.y + b.y, 0.f);
    v.z = fmaxf(v.z + b.z, 0.f);
    v.w = fmaxf(v.w + b.w, 0.f);
    op[0] = v;
}

extern "C" void kernel_launch(void* const* d_in, const int* in_sizes, int n_in,
                              void* d_out, int out_size, void* d_ws, size_t ws_size,
                              hipStream_t stream) {
    const float* x    = (const float*)d_in[0];   // [N,16] f32
    const int*   ei   = (const int*)d_in[1];     // [2,E] int64 (runtime-verified) or int32
    const float* ea   = (const float*)d_in[2];   // [E,8] f32
    const float* W    = (const float*)d_in[3];   // [8,16,16] f32
    const float* bias = (const float*)d_in[4];   // [16] f32
    float* out = (float*)d_out;

    int n_nodes = in_sizes[0] / IN_C;
    long long n_edges = in_sizes[2] / NA;

    // fp32 accumulator is d_out itself
    hipMemsetAsync(d_out, 0, (size_t)n_nodes * OUT_C * sizeof(float), stream);

    long long tE = n_edges * OUT_C;
    int gE = (int)((tE + 255) / 256);

    size_t y_bytes = (size_t)n_nodes * OUT_C * NA * sizeof(u16);  // 25.6 MB
    if (ws_size >= 64 + y_bytes) {
        int* flag = (int*)d_ws;
        u16* y = (u16*)((char*)d_ws + 64);
        int t1 = n_nodes * OUT_C;
        k_stage1<<<(t1 + 255) / 256, 256, 0, stream>>>(x, W, ei, n_edges, y, flag, n_nodes);
        k_stage2<<<gE, 256, 0, stream>>>(ei, ea, y, out, flag, n_edges);
    } else {
        k_direct<<<gE, 256, 0, stream>>>(x, ei, ea, W, out, n_edges);
    }

    int t4 = (n_nodes * OUT_C) / 4;
    k_bias_relu<<<(t4 + 255) / 256, 256, 0, stream>>>(bias, out, t4);
}